// Round 2
// baseline (467.620 us; speedup 1.0000x reference)
//
#include <hip/hip_runtime.h>

#define B_ 4096
#define D_ 512
#define K_ 10
#define L_ 256
#define V_ 80

// ---------------------------------------------------------------------------
// Fully fused: one 256-thread block per batch row. No workspace usage.
//
// Stage A (GEMV):  raw[j] = dot(x[row,:], W[:,j]) + b[j],  j in [0,30)
//   4 waves; wave w computes cols [8w, 8w+8) (wave 3: 6 cols).
//   Lane-strided D loop -> coalesced x loads; W rows via L1.
// Stage B:         alpha/beta/kappa from raw, kappa -> d_out.
// Stage C:         phi[l] for l < seqlen; scatter one-hot prefix into w[80].
// ---------------------------------------------------------------------------
__global__ __launch_bounds__(256) void fused_kernel(
    const float* __restrict__ x,           // [B, D]
    const float* __restrict__ prev_kappa,  // [B, K]
    const float* __restrict__ oh,          // [B, L, V]
    const int*   __restrict__ seqlen,      // [B]
    const float* __restrict__ W,           // [D, 3K]
    const float* __restrict__ bias,        // [3K]
    const float* __restrict__ kappa_scale, // [1]
    float* __restrict__ out_w,             // [B, V]
    float* __restrict__ out_kappa)         // [B, K]
{
    const int b    = blockIdx.x;
    const int tid  = threadIdx.x;
    const int wave = tid >> 6;
    const int lane = tid & 63;

    __shared__ float s_raw[32];
    __shared__ float s_a[K_], s_b[K_], s_k[K_];
    __shared__ float s_phi[L_];
    __shared__ float s_w[V_];

    // ---- Stage A: GEMV ----
    const float* xr = x + (size_t)b * D_;
    const int jbase = wave * 8;
    const int jcnt  = (jbase < 24) ? 8 : 6;   // wave 3 covers cols 24..29

    float acc[8];
#pragma unroll
    for (int jj = 0; jj < 8; ++jj) acc[jj] = 0.f;

#pragma unroll
    for (int i = 0; i < 8; ++i) {
        const int d = lane + 64 * i;
        const float xv = xr[d];
        const float* wrow = W + d * 30 + jbase;
#pragma unroll
        for (int jj = 0; jj < 8; ++jj) {
            if (jj < 6 || jbase < 24)   // compile-time-foldable guard per wave
                acc[jj] = fmaf(xv, wrow[jj], acc[jj]);
        }
    }

#pragma unroll
    for (int jj = 0; jj < 8; ++jj) {
#pragma unroll
        for (int s = 32; s >= 1; s >>= 1)
            acc[jj] += __shfl_xor(acc[jj], s, 64);
    }

    if (lane < jcnt) {
        float v = acc[0];
#pragma unroll
        for (int jj = 1; jj < 8; ++jj) v = (lane == jj) ? acc[jj] : v;
        s_raw[jbase + lane] = v;
    }
    if (tid < V_) s_w[tid] = 0.f;
    __syncthreads();

    // ---- Stage B: activations ----
    if (tid < K_) {
        const float a_hat = s_raw[tid]      + bias[tid];
        const float b_hat = s_raw[10 + tid] + bias[10 + tid];
        const float k_hat = s_raw[20 + tid] + bias[20 + tid];

        s_a[tid] = __expf(fminf(fmaxf(a_hat, -8.f), 8.f));
        s_b[tid] = __expf(fminf(fmaxf(b_hat, -8.f), 8.f));
        const float dk = __expf(fminf(fmaxf(k_hat + kappa_scale[0], -8.f), 5.f));
        const float kp = prev_kappa[b * K_ + tid] + dk;
        s_k[tid] = kp;
        out_kappa[b * K_ + tid] = kp;
    }
    const int sl = seqlen[b];
    __syncthreads();

    // ---- Stage C: phi ----
    if (tid < sl) {
        const float u = (float)(tid + 1);
        float phi = 0.f;
#pragma unroll
        for (int k = 0; k < K_; ++k) {
            const float diff = s_k[k] - u;
            float e = -s_b[k] * diff * diff;   // always <= 0
            e = fmaxf(e, -50.f);
            phi = fmaf(s_a[k], __expf(e), phi);
        }
        s_phi[tid] = phi;
    }
    __syncthreads();

    // ---- scatter the one-hot prefix (sl*80 floats, multiple of 4) ----
    const int total4 = sl * (V_ / 4);
    const float4* ohb = (const float4*)(oh + (size_t)b * (L_ * V_));
    for (int f = tid; f < total4; f += 256) {
        const float4 vals = ohb[f];
        const int base = f * 4;
        const float vv[4] = {vals.x, vals.y, vals.z, vals.w};
#pragma unroll
        for (int c = 0; c < 4; ++c) {
            if (vv[c] != 0.f) {
                const int idx = base + c;
                const int l = idx / V_;
                const int v = idx - l * V_;
                atomicAdd(&s_w[v], s_phi[l] * vv[c]);
            }
        }
    }
    __syncthreads();

    if (tid < V_) out_w[b * V_ + tid] = s_w[tid];
}

extern "C" void kernel_launch(void* const* d_in, const int* in_sizes, int n_in,
                              void* d_out, int out_size, void* d_ws, size_t ws_size,
                              hipStream_t stream) {
    const float* x          = (const float*)d_in[0];
    const float* prev_kappa = (const float*)d_in[1];
    const float* oh         = (const float*)d_in[2];
    const int*   seqlen     = (const int*)d_in[3];
    const float* W          = (const float*)d_in[4];
    const float* bias       = (const float*)d_in[5];
    const float* kscale     = (const float*)d_in[6];

    float* out   = (float*)d_out;
    float* out_w = out;              // [B, V]
    float* out_k = out + B_ * V_;    // [B, K]

    fused_kernel<<<B_, 256, 0, stream>>>(x, prev_kappa, oh, seqlen, W, bias,
                                         kscale, out_w, out_k);
}

// Round 3
// 434.914 us; speedup vs baseline: 1.0752x; 1.0752x over previous
//
#include <hip/hip_runtime.h>

#define B_ 4096
#define D_ 512
#define K_ 10
#define L_ 256
#define V_ 80

// ---------------------------------------------------------------------------
// Kernel 1: GEMV + activations. 4 rows per 256-thread block (1024 blocks).
// Wave w computes cols [8w, 8w+8) (wave 3: 6 cols) for all 4 rows, so each
// W cache line is touched once per wave but serves 4 rows of FMAs.
// alpha/beta -> ws ; kappa -> d_out slot.
// ---------------------------------------------------------------------------
__global__ __launch_bounds__(256) void gemv_kernel(
    const float* __restrict__ x,           // [B, D]
    const float* __restrict__ prev_kappa,  // [B, K]
    const float* __restrict__ W,           // [D, 3K]
    const float* __restrict__ bias,        // [3K]
    const float* __restrict__ kscale,      // [1]
    float* __restrict__ ws_alpha,          // [B, K]
    float* __restrict__ ws_beta,           // [B, K]
    float* __restrict__ out_kappa)         // [B, K]
{
    const int tid  = threadIdx.x;
    const int wave = tid >> 6;
    const int lane = tid & 63;
    const int r0   = blockIdx.x * 4;
    const int jbase = wave * 8;
    const int jcnt  = (wave == 3) ? 6 : 8;

    const float* xb = x + (size_t)r0 * D_;

    float acc[4][8];
#pragma unroll
    for (int r = 0; r < 4; ++r)
#pragma unroll
        for (int jj = 0; jj < 8; ++jj) acc[r][jj] = 0.f;

#pragma unroll
    for (int i = 0; i < 8; ++i) {
        const int d = lane + 64 * i;
        const float* wrow = W + d * 30 + jbase;
        float wv[8];
#pragma unroll
        for (int jj = 0; jj < 8; ++jj)
            wv[jj] = (jj < 6 || wave < 3) ? wrow[jj] : 0.f;  // guard OOB for wave 3
#pragma unroll
        for (int r = 0; r < 4; ++r) {
            const float xv = xb[r * D_ + d];
#pragma unroll
            for (int jj = 0; jj < 8; ++jj)
                acc[r][jj] = fmaf(xv, wv[jj], acc[r][jj]);
        }
    }

#pragma unroll
    for (int r = 0; r < 4; ++r)
#pragma unroll
        for (int jj = 0; jj < 8; ++jj)
#pragma unroll
            for (int s = 32; s >= 1; s >>= 1)
                acc[r][jj] += __shfl_xor(acc[r][jj], s, 64);

    __shared__ float s_raw[4][30];
    if (lane < jcnt) {
#pragma unroll
        for (int r = 0; r < 4; ++r) {
            float v = acc[r][0];
#pragma unroll
            for (int jj = 1; jj < 8; ++jj) v = (lane == jj) ? acc[r][jj] : v;
            s_raw[r][jbase + lane] = v;
        }
    }
    __syncthreads();

    if (tid < 40) {
        const int r = tid / 10;
        const int k = tid - r * 10;
        const int row = r0 + r;

        const float a_hat = s_raw[r][k]      + bias[k];
        const float b_hat = s_raw[r][10 + k] + bias[10 + k];
        const float k_hat = s_raw[r][20 + k] + bias[20 + k];

        ws_alpha[row * K_ + k] = __expf(fminf(fmaxf(a_hat, -8.f), 8.f));
        ws_beta[row * K_ + k]  = __expf(fminf(fmaxf(b_hat, -8.f), 8.f));
        const float dk = __expf(fminf(fmaxf(k_hat + kscale[0], -8.f), 5.f));
        out_kappa[row * K_ + k] = prev_kappa[row * K_ + k] + dk;
    }
}

// ---------------------------------------------------------------------------
// Kernel 2: phi + one-hot prefix scatter. One 256-thread block per row.
// Two independent float4 loads per loop iteration (2 outstanding VMEMs).
// Note 80/4 = 20 float4 per l, so all 4 components of a float4 share l.
// ---------------------------------------------------------------------------
__global__ __launch_bounds__(256) void scatter_kernel(
    const float* __restrict__ oh,        // [B, L, V]
    const int*   __restrict__ seqlen,    // [B]
    const float* __restrict__ ws_alpha,  // [B, K]
    const float* __restrict__ ws_beta,   // [B, K]
    const float* __restrict__ kappa,     // [B, K] (from d_out)
    float* __restrict__ out_w)           // [B, V]
{
    const int b   = blockIdx.x;
    const int tid = threadIdx.x;

    __shared__ float s_a[K_], s_b[K_], s_k[K_];
    __shared__ float s_phi[L_];
    __shared__ float s_w[V_];

    if (tid < K_) {
        s_a[tid] = ws_alpha[b * K_ + tid];
        s_b[tid] = ws_beta[b * K_ + tid];
        s_k[tid] = kappa[b * K_ + tid];
    }
    if (tid < V_) s_w[tid] = 0.f;

    const int sl = seqlen[b];
    __syncthreads();

    if (tid < sl) {
        const float u = (float)(tid + 1);
        float phi = 0.f;
#pragma unroll
        for (int k = 0; k < K_; ++k) {
            const float diff = s_k[k] - u;
            float e = fmaxf(-s_b[k] * diff * diff, -50.f);
            phi = fmaf(s_a[k], __expf(e), phi);
        }
        s_phi[tid] = phi;
    }
    __syncthreads();

    const int total4 = sl * (V_ / 4);   // float4 count of the prefix
    const float4* ohb = (const float4*)(oh + (size_t)b * (L_ * V_));

    for (int f = tid; f < total4; f += 512) {
        const float4 v0 = ohb[f];
        const int f1 = f + 256;
        const bool has1 = (f1 < total4);
        float4 v1 = make_float4(0.f, 0.f, 0.f, 0.f);
        if (has1) v1 = ohb[f1];

        {
            const int l  = f / 20;            // 20 float4 per l
            const int vb = (f - l * 20) * 4;
            const float p = s_phi[l];
            if (v0.x != 0.f) atomicAdd(&s_w[vb + 0], p * v0.x);
            if (v0.y != 0.f) atomicAdd(&s_w[vb + 1], p * v0.y);
            if (v0.z != 0.f) atomicAdd(&s_w[vb + 2], p * v0.z);
            if (v0.w != 0.f) atomicAdd(&s_w[vb + 3], p * v0.w);
        }
        if (has1) {
            const int l  = f1 / 20;
            const int vb = (f1 - l * 20) * 4;
            const float p = s_phi[l];
            if (v1.x != 0.f) atomicAdd(&s_w[vb + 0], p * v1.x);
            if (v1.y != 0.f) atomicAdd(&s_w[vb + 1], p * v1.y);
            if (v1.z != 0.f) atomicAdd(&s_w[vb + 2], p * v1.z);
            if (v1.w != 0.f) atomicAdd(&s_w[vb + 3], p * v1.w);
        }
    }
    __syncthreads();

    if (tid < V_) out_w[b * V_ + tid] = s_w[tid];
}

extern "C" void kernel_launch(void* const* d_in, const int* in_sizes, int n_in,
                              void* d_out, int out_size, void* d_ws, size_t ws_size,
                              hipStream_t stream) {
    const float* x          = (const float*)d_in[0];
    const float* prev_kappa = (const float*)d_in[1];
    const float* oh         = (const float*)d_in[2];
    const int*   seqlen     = (const int*)d_in[3];
    const float* W          = (const float*)d_in[4];
    const float* bias       = (const float*)d_in[5];
    const float* kscale     = (const float*)d_in[6];

    float* out   = (float*)d_out;
    float* out_w = out;              // [B, V]
    float* out_k = out + B_ * V_;    // [B, K]

    float* wsf      = (float*)d_ws;
    float* ws_alpha = wsf;               // B*K floats
    float* ws_beta  = wsf + B_ * K_;     // B*K floats

    gemv_kernel<<<B_ / 4, 256, 0, stream>>>(x, prev_kappa, W, bias, kscale,
                                            ws_alpha, ws_beta, out_k);
    scatter_kernel<<<B_, 256, 0, stream>>>(oh, seqlen, ws_alpha, ws_beta, out_k,
                                           out_w);
}